// Round 7
// baseline (37211.301 us; speedup 1.0000x reference)
//
#include <hip/hip_runtime.h>

#define HIDDEN 256
#define TENC 336
#define HORIZ 168
#define BSZ 1024
#define BH (BSZ*HIDDEN)   // f16 elements per h snapshot (512 KiB)

typedef _Float16 f16;
typedef f16 f16x8 __attribute__((ext_vector_type(8)));
typedef float f32x4 __attribute__((ext_vector_type(4)));
typedef unsigned int u32;
typedef unsigned long long u64;

// ---- workspace layout ----
#define H0_OFF 0                        // 3 slots x 512K
#define H1_OFF (3*BH*2)                 // 2 slots x 512K
#define PP_OFF (H1_OFF + 2*BH*2)        // 2 slots x [1024][16] f32
#define F0_OFF (PP_OFF + 2*BSZ*16*4)    // 1024 lines x 64B
#define F1_OFF (F0_OFF + 1024*64)
#define WS_TOTAL (F1_OFF + 1024*64)

__device__ __forceinline__ float sigm(float x){ return 1.0f/(1.0f+__expf(-x)); }
__device__ __forceinline__ float tanh_f(float x){ return 2.0f/(1.0f+__expf(-2.0f*x)) - 1.0f; }

// ---- proven agent-scope flag primitives (R1/R6) ----
__device__ __forceinline__ u32 ald32(const u32* p){
  return __hip_atomic_load(p, __ATOMIC_RELAXED, __HIP_MEMORY_SCOPE_AGENT);
}
__device__ __forceinline__ void ast32(u32* p, u32 v){
  __hip_atomic_store(p, v, __ATOMIC_RELAXED, __HIP_MEMORY_SCOPE_AGENT);
}

// B-fragment from f32 weights: lane holds W[grow(col=lane&15)][k..k+7]
__device__ __forceinline__ f16x8 loadWfrag(const float* W, int grow, int k){
  const float* p = W + grow*HIDDEN + k;
  float4 lo = *(const float4*)p;
  float4 hi = *(const float4*)(p+4);
  f16x8 r;
  r[0]=(f16)lo.x; r[1]=(f16)lo.y; r[2]=(f16)lo.z; r[3]=(f16)lo.w;
  r[4]=(f16)hi.x; r[5]=(f16)hi.y; r[6]=(f16)hi.z; r[7]=(f16)hi.w;
  return r;
}

// per-wave poll with s_sleep backoff; acquire fence on success.
// lanes 0..15 poll f0 member lines (stride 64 u32), lanes 16..31 poll f1.
__device__ __forceinline__ void pollw2(const u32* f0, u32 t0, const u32* f1, u32 t1, int lane){
  const u32* sp = nullptr; u32 tgt = 0;
  if (lane < 16){ sp = f0 + lane*64; tgt = t0; }
  else if (f1 != nullptr && lane < 32){ sp = f1 + (lane-16)*64; tgt = t1; }
  for (int it = 0; it < (1<<20); ++it){
    bool ok = (sp == nullptr) || (ald32(sp) >= tgt);
    if (__all((int)ok)) break;
    __builtin_amdgcn_s_sleep(1);
  }
  __threadfence();   // acquire: invalidate stale cached exchange data
}

// per-wave release signal: fence (drain + L2 writeback) then one flag store
__device__ __forceinline__ void sigw(u32* line, u32 v, int lane){
  __threadfence();   // release: plain h/pp stores visible at coherence point
  if (lane == 0) ast32(line, v);
}

// load 8 A-fragments from member-contiguous layout (fully coalesced):
// slice idx = j*256 + row*16 + d ; fragment k = kt*32 + 8*hi
__device__ __forceinline__ void loadA8n(f16x8* a, const f16* slotu, int lane){
  const int r16 = (lane & 15) * 16;
  const int h8  = ((lane >> 4) & 1) * 8;
  const int jb  = lane >> 5;
  #pragma unroll
  for (int kt=0; kt<8; ++kt){
    int j = kt*2 + jb;
    a[kt] = *(const f16x8*)(slotu + j*256 + r16 + h8);
  }
}

__device__ __forceinline__ void mm4(f32x4* acc, const f16x8* a, const f16x8 B[4][8]){
  #pragma unroll
  for (int kt=0; kt<8; ++kt){
    #pragma unroll
    for (int n=0; n<4; ++n)
      acc[n] = __builtin_amdgcn_mfma_f32_16x16x32_f16(a[kt], B[n][kt], acc[n], 0,0,0);
  }
}
__device__ __forceinline__ void mm4l(f32x4* acc, const f16x8* a, const char* WL, int lane){
  #pragma unroll
  for (int kt=0; kt<8; ++kt){
    #pragma unroll
    for (int n=0; n<4; ++n){
      f16x8 bf = *(const f16x8*)(WL + ((n*8+kt)*64 + lane)*16);
      acc[n] = __builtin_amdgcn_mfma_f32_16x16x32_f16(a[kt], bf, acc[n], 0,0,0);
    }
  }
}

// in-register LSTM cell: lane owns (4 rows, 1 dim); acc[n][q] = gate n, row q
__device__ __forceinline__ void cell4(const f32x4* acc, const float* b, const float* wx,
                                      const float* x4, float* c, float* h4){
  #pragma unroll
  for (int q=0; q<4; ++q){
    float pi = acc[0][q] + b[0] + x4[q]*wx[0];
    float pf = acc[1][q] + b[1] + x4[q]*wx[1];
    float pg = acc[2][q] + b[2] + x4[q]*wx[2];
    float po = acc[3][q] + b[3] + x4[q]*wx[3];
    float i = sigm(pi), f = sigm(pf), gg = tanh_f(pg), o = sigm(po);
    c[q] = f*c[q] + i*gg;
    h4[q] = o*tanh_f(c[q]);
  }
}

// transpose 16x16 slice through per-wave LDS scratch, store one coalesced
// u64 per lane into member-contiguous layout (512B contiguous per wave)
__device__ __forceinline__ void storeHn(f16* slotbase, int u, int j, f16* tsc,
                                        const float* h4, int hi, int d, int lane){
  #pragma unroll
  for (int q=0; q<4; ++q) tsc[(hi*4+q)*16 + d] = (f16)h4[q];
  asm volatile("s_waitcnt lgkmcnt(0)" ::: "memory");
  __builtin_amdgcn_sched_barrier(0);
  u64 v = *(const u64*)(tsc + lane*4);
  *(u64*)(slotbase + u*4096 + j*256 + lane*4) = v;
}

struct P {
  const float *x;
  const float *eWih0,*eWhh0,*eBih0,*eBhh0,*eWih1,*eWhh1,*eBih1,*eBhh1;
  const float *dWih0,*dWhh0,*dBih0,*dBhh0,*dWih1,*dWhh1,*dBih1,*dBhh1;
  const float *fcW,*fcB;
  float* out;
  char* ws;
};

__global__ void initk(char* ws){
  u32* p = (u32*)ws;
  size_t total = (size_t)WS_TOTAL / 4;
  for (size_t k = (size_t)blockIdx.x*blockDim.x + threadIdx.x; k < total;
       k += (size_t)gridDim.x*blockDim.x) p[k] = 0u;
}

__global__ __launch_bounds__(512) void lstm_main(P p){
  const int tid  = threadIdx.x;
  const int lane = tid & 63;
  const int w    = tid >> 6;
  const int chain= w >> 2;         // 0 = L0 chain, 1 = L1 chain
  const int v    = w & 3;          // row-quarter unit
  const int g    = blockIdx.x & 15;
  const int j    = blockIdx.x >> 4;
  const int hi   = lane >> 4;      // row sub-block
  const int d    = lane & 15;      // dim within slice
  const int D    = j*16 + d;       // global h dim
  const int unit = g*4 + v;

  __shared__ __align__(16) char sWL[32768];   // Whh1 / dWhh1 fragments
  __shared__ __align__(16) f16  sTR[8][256];  // per-wave transpose scratch

  f16*   h0buf = (f16*)(p.ws + H0_OFF);
  f16*   h1buf = (f16*)(p.ws + H1_OFF);
  float* ppart = (float*)(p.ws + PP_OFF);
  u32*   F0    = (u32*)(p.ws + F0_OFF);
  u32*   F1    = (u32*)(p.ws + F1_OFF);
  const u32* pF0 = F0 + ((g*16 + 0)*4 + v)*16;   // member stride = 64 u32
  const u32* pF1 = F1 + ((g*16 + 0)*4 + v)*16;
  u32* myF0 = F0 + ((g*16 + j)*4 + v)*16;
  u32* myF1 = F1 + ((g*16 + j)*4 + v)*16;
  f16* tsc = sTR[w];

  int rows[4];
  #pragma unroll
  for (int q=0; q<4; ++q) rows[q] = g*64 + v*16 + hi*4 + q;

  f16x8 B[4][8];
  float c[4] = {0.f,0.f,0.f,0.f};
  float wx[4], b0[4];
  float fcw = 0.f, fcb = 0.f;

  // ---- init: weights into VGPR/LDS ----
  if (chain == 0){
    #pragma unroll
    for (int n=0; n<4; ++n){
      #pragma unroll
      for (int kt=0; kt<8; ++kt)
        B[n][kt] = loadWfrag(p.eWhh0, n*256 + j*16 + d, kt*32 + 8*hi);
      wx[n] = p.eWih0[n*256 + D];
      b0[n] = p.eBih0[n*256 + D] + p.eBhh0[n*256 + D];
    }
  } else {
    #pragma unroll
    for (int n=0; n<4; ++n){
      #pragma unroll
      for (int kt=0; kt<8; ++kt)
        B[n][kt] = loadWfrag(p.eWih1, n*256 + j*16 + d, kt*32 + 8*hi);
      wx[n] = 0.f;
      b0[n] = p.eBih1[n*256 + D] + p.eBhh1[n*256 + D];
    }
    #pragma unroll
    for (int kt=0; kt<8; ++kt)
      *(f16x8*)(sWL + ((v*8+kt)*64 + lane)*16) =
        loadWfrag(p.eWhh1, v*256 + j*16 + d, kt*32 + 8*hi);
  }
  __syncthreads();

  // ================= ENCODER (chains run concurrently) =====================
  if (chain == 0){
    for (int r = 0; r < TENC; ++r){
      float x4[4];
      #pragma unroll
      for (int q=0; q<4; ++q) x4[q] = p.x[rows[q]*TENC + r];
      pollw2(pF0, (u32)r, pF1, (r>=2)?(u32)(r-2):0u, lane);
      f16x8 a[8];
      loadA8n(a, h0buf + ((r+2)%3)*BH + unit*4096, lane);
      f32x4 acc[4] = {{0,0,0,0},{0,0,0,0},{0,0,0,0},{0,0,0,0}};
      mm4(acc, a, B);
      float h4[4];
      cell4(acc, b0, wx, x4, c, h4);
      storeHn(h0buf + (r%3)*BH, unit, j, tsc, h4, hi, d, lane);
      sigw(myF0, (u32)(r+1), lane);
    }
  } else {
    for (int r = 0; r < TENC; ++r){
      pollw2(pF0, (u32)(r+1), pF1, (u32)r, lane);   // h0(r) fresh, h1(r-1)
      f16x8 a0[8], a1[8];
      loadA8n(a0, h0buf + (r%3)*BH + unit*4096, lane);
      loadA8n(a1, h1buf + ((r+1)&1)*BH + unit*4096, lane);
      f32x4 acc[4] = {{0,0,0,0},{0,0,0,0},{0,0,0,0},{0,0,0,0}};
      mm4(acc, a0, B);          // Wih1 * h0(r)
      mm4l(acc, a1, sWL, lane); // Whh1 * h1(r-1)
      float h4[4], xz[4] = {0.f,0.f,0.f,0.f};
      cell4(acc, b0, wx, xz, c, h4);
      storeHn(h1buf + (r&1)*BH, unit, j, tsc, h4, hi, d, lane);
      sigw(myF1, (u32)(r+1), lane);
    }
  }

  // ---- swap to decoder weights ----
  __syncthreads();
  if (chain == 0){
    #pragma unroll
    for (int n=0; n<4; ++n){
      #pragma unroll
      for (int kt=0; kt<8; ++kt)
        B[n][kt] = loadWfrag(p.dWhh0, n*256 + j*16 + d, kt*32 + 8*hi);
      wx[n] = p.dWih0[n*256 + D];
      b0[n] = p.dBih0[n*256 + D] + p.dBhh0[n*256 + D];
    }
    fcb = p.fcB[0];
  } else {
    #pragma unroll
    for (int n=0; n<4; ++n){
      #pragma unroll
      for (int kt=0; kt<8; ++kt)
        B[n][kt] = loadWfrag(p.dWih1, n*256 + j*16 + d, kt*32 + 8*hi);
      b0[n] = p.dBih1[n*256 + D] + p.dBhh1[n*256 + D];
    }
    #pragma unroll
    for (int kt=0; kt<8; ++kt)
      *(f16x8*)(sWL + ((v*8+kt)*64 + lane)*16) =
        loadWfrag(p.dWhh1, v*256 + j*16 + d, kt*32 + 8*hi);
    fcw = p.fcW[D];
  }
  __syncthreads();

  // ================= DECODER (ping-pong between chains) ====================
  if (chain == 0){
    for (int t = 0; t < HORIZ; ++t){
      float inp4[4];
      if (t == 0){
        #pragma unroll
        for (int q=0; q<4; ++q) inp4[q] = p.x[rows[q]*TENC + (TENC-1)];
      }
      pollw2(pF0, (u32)(336+t), pF1, (t==0)?335u:(u32)(336+t), lane);
      if (t > 0){
        float pp4[4];
        #pragma unroll
        for (int q=0; q<4; ++q) pp4[q] = ppart[((t-1)&1)*BSZ*16 + rows[q]*16 + d];
        #pragma unroll
        for (int q=0; q<4; ++q){
          float s = pp4[q];
          s += __shfl_xor(s, 1); s += __shfl_xor(s, 2);
          s += __shfl_xor(s, 4); s += __shfl_xor(s, 8);
          inp4[q] = s + fcb;
        }
      }
      f16x8 a[8];
      loadA8n(a, h0buf + ((335+t)%3)*BH + unit*4096, lane);
      f32x4 acc[4] = {{0,0,0,0},{0,0,0,0},{0,0,0,0},{0,0,0,0}};
      mm4(acc, a, B);
      float h4[4];
      cell4(acc, b0, wx, inp4, c, h4);
      storeHn(h0buf + ((336+t)%3)*BH, unit, j, tsc, h4, hi, d, lane);
      if (t > 0 && j == 0 && d == 0){
        #pragma unroll
        for (int q=0; q<4; ++q) p.out[rows[q]*HORIZ + (t-1)] = inp4[q];
      }
      sigw(myF0, (u32)(337+t), lane);
    }
    // final column: pred(167)
    if (j == 0){
      pollw2(pF1, 504u, nullptr, 0, lane);
      #pragma unroll
      for (int q=0; q<4; ++q){
        float s = ppart[(167&1)*BSZ*16 + rows[q]*16 + d];
        s += __shfl_xor(s, 1); s += __shfl_xor(s, 2);
        s += __shfl_xor(s, 4); s += __shfl_xor(s, 8);
        if (d == 0) p.out[rows[q]*HORIZ + (HORIZ-1)] = s + fcb;
      }
    }
  } else {
    for (int t = 0; t < HORIZ; ++t){
      pollw2(pF0, (u32)(337+t), pF1, (u32)(336+t), lane);  // h0(t) fresh, h1(t-1)
      f16x8 a0[8], a1[8];
      loadA8n(a0, h0buf + ((336+t)%3)*BH + unit*4096, lane);
      loadA8n(a1, h1buf + ((t+1)&1)*BH + unit*4096, lane);
      f32x4 acc[4] = {{0,0,0,0},{0,0,0,0},{0,0,0,0},{0,0,0,0}};
      mm4(acc, a0, B);          // dWih1 * h0(t)
      mm4l(acc, a1, sWL, lane); // dWhh1 * h1(t-1)
      float h4[4], xz[4] = {0.f,0.f,0.f,0.f};
      cell4(acc, b0, wx, xz, c, h4);
      storeHn(h1buf + (t&1)*BH, unit, j, tsc, h4, hi, d, lane);
      // pred partial for this member: sum over our 16 dims
      #pragma unroll
      for (int q=0; q<4; ++q){
        float s = fcw * h4[q];
        s += __shfl_xor(s, 1); s += __shfl_xor(s, 2);
        s += __shfl_xor(s, 4); s += __shfl_xor(s, 8);
        if (d == 0)
          ppart[(t&1)*BSZ*16 + rows[q]*16 + j] = s;
      }
      sigw(myF1, (u32)(337+t), lane);
    }
  }
}

extern "C" void kernel_launch(void* const* d_in, const int* in_sizes, int n_in,
                              void* d_out, int out_size, void* d_ws, size_t ws_size,
                              hipStream_t stream) {
  (void)in_sizes; (void)n_in; (void)out_size;
  if (ws_size < (size_t)WS_TOTAL) return;  // fail visibly (poisoned output)

  P prm;
  prm.x     = (const float*)d_in[0];
  prm.eWih0 = (const float*)d_in[1];  prm.eWhh0 = (const float*)d_in[2];
  prm.eBih0 = (const float*)d_in[3];  prm.eBhh0 = (const float*)d_in[4];
  prm.eWih1 = (const float*)d_in[5];  prm.eWhh1 = (const float*)d_in[6];
  prm.eBih1 = (const float*)d_in[7];  prm.eBhh1 = (const float*)d_in[8];
  prm.dWih0 = (const float*)d_in[9];  prm.dWhh0 = (const float*)d_in[10];
  prm.dBih0 = (const float*)d_in[11]; prm.dBhh0 = (const float*)d_in[12];
  prm.dWih1 = (const float*)d_in[13]; prm.dWhh1 = (const float*)d_in[14];
  prm.dBih1 = (const float*)d_in[15]; prm.dBhh1 = (const float*)d_in[16];
  prm.fcW   = (const float*)d_in[17]; prm.fcB   = (const float*)d_in[18];
  prm.out   = (float*)d_out;
  prm.ws    = (char*)d_ws;

  hipLaunchKernelGGL(initk, dim3(256), dim3(256), 0, stream, (char*)d_ws);

  void* args[] = { &prm };
  hipLaunchCooperativeKernel((const void*)lstm_main, dim3(256), dim3(512),
                             args, 0, stream);
}

// Round 8
// 9084.619 us; speedup vs baseline: 4.0961x; 4.0961x over previous
//
#include <hip/hip_runtime.h>

#define HIDDEN 256
#define TENC 336
#define HORIZ 168
#define BSZ 1024
#define BH (BSZ*HIDDEN)   // f16 elements per h snapshot (512 KiB)

typedef _Float16 f16;
typedef f16 f16x8 __attribute__((ext_vector_type(8)));
typedef float f32x4 __attribute__((ext_vector_type(4)));
typedef unsigned int u32;
typedef unsigned long long u64;

// ---- workspace layout ----
#define H0_OFF 0                        // 3 slots x 512K
#define H1_OFF (3*BH*2)                 // 2 slots x 512K
#define PP_OFF (H1_OFF + 2*BH*2)        // 2 slots x [1024][16] f32
#define F0_OFF (PP_OFF + 2*BSZ*16*4)    // 64 packed lines (16 groups x 4 units) x 64B
#define F1_OFF (F0_OFF + 64*64)
#define WS_TOTAL (F1_OFF + 64*64)

__device__ __forceinline__ float sigm(float x){ return 1.0f/(1.0f+__expf(-x)); }
__device__ __forceinline__ float tanh_f(float x){ return 2.0f/(1.0f+__expf(-2.0f*x)) - 1.0f; }

// ---- proven agent-scope primitives (R1/R6) ----
__device__ __forceinline__ u64 ald64(const void* p){
  return __hip_atomic_load((const u64*)p, __ATOMIC_RELAXED, __HIP_MEMORY_SCOPE_AGENT);
}
__device__ __forceinline__ u32 ald32(const u32* p){
  return __hip_atomic_load(p, __ATOMIC_RELAXED, __HIP_MEMORY_SCOPE_AGENT);
}
__device__ __forceinline__ float aldf(const float* p){
  return __hip_atomic_load(p, __ATOMIC_RELAXED, __HIP_MEMORY_SCOPE_AGENT);
}
__device__ __forceinline__ void ast32(u32* p, u32 v){
  __hip_atomic_store(p, v, __ATOMIC_RELAXED, __HIP_MEMORY_SCOPE_AGENT);
}
__device__ __forceinline__ void ast64(u64* p, u64 v){
  __hip_atomic_store(p, v, __ATOMIC_RELAXED, __HIP_MEMORY_SCOPE_AGENT);
}

// B-fragment from f32 weights: lane holds W[grow(col=lane&15)][k..k+7]
__device__ __forceinline__ f16x8 loadWfrag(const float* W, int grow, int k){
  const float* p = W + grow*HIDDEN + k;
  float4 lo = *(const float4*)p;
  float4 hi = *(const float4*)(p+4);
  f16x8 r;
  r[0]=(f16)lo.x; r[1]=(f16)lo.y; r[2]=(f16)lo.z; r[3]=(f16)lo.w;
  r[4]=(f16)hi.x; r[5]=(f16)hi.y; r[6]=(f16)hi.z; r[7]=(f16)hi.w;
  return r;
}

// per-wave poll on PACKED flag lines: f0/f1 each point at a 64B line holding
// 16 member dwords. lanes 0..15 read f0[lane] (one broadcast transaction),
// lanes 16..31 read f1[lane-16]. Bounded; relaxed atomics (R6 semantics).
__device__ __forceinline__ void pollw2(const u32* f0, u32 t0, const u32* f1, u32 t1, int lane){
  const u32* sp = nullptr; u32 tgt = 0;
  if (lane < 16){ sp = f0 + lane; tgt = t0; }
  else if (f1 != nullptr && lane < 32){ sp = f1 + (lane-16); tgt = t1; }
  for (int it = 0; it < (1<<20); ++it){
    bool ok = (sp == nullptr) || (ald32(sp) >= tgt);
    if (__all((int)ok)) break;
  }
}

// per-wave release: drain this wave's (uncached) h-stores, then one flag store
__device__ __forceinline__ void sigw(u32* line, u32 v, int lane){
  asm volatile("s_waitcnt vmcnt(0)" ::: "memory");
  if (lane == 0) ast32(line, v);
}

// load 8 A-fragments from member-contiguous layout [j][row16][d16] (coalesced):
__device__ __forceinline__ void loadA8n(f16x8* a, const f16* slotu, int lane){
  const int r16 = (lane & 15) * 16;
  const int h8  = ((lane >> 4) & 1) * 8;
  const int jb  = lane >> 5;
  #pragma unroll
  for (int kt=0; kt<8; ++kt){
    const f16* q = slotu + (kt*2 + jb)*256 + r16 + h8;
    union { u64 w[2]; f16x8 v; } u;
    u.w[0] = ald64(q); u.w[1] = ald64(q+4);
    a[kt] = u.v;
  }
}

__device__ __forceinline__ void mm4(f32x4* acc, const f16x8* a, const f16x8 B[4][8]){
  #pragma unroll
  for (int kt=0; kt<8; ++kt){
    #pragma unroll
    for (int n=0; n<4; ++n)
      acc[n] = __builtin_amdgcn_mfma_f32_16x16x32_f16(a[kt], B[n][kt], acc[n], 0,0,0);
  }
}
__device__ __forceinline__ void mm4l(f32x4* acc, const f16x8* a, const char* WL, int lane){
  #pragma unroll
  for (int kt=0; kt<8; ++kt){
    #pragma unroll
    for (int n=0; n<4; ++n){
      f16x8 bf = *(const f16x8*)(WL + ((n*8+kt)*64 + lane)*16);
      acc[n] = __builtin_amdgcn_mfma_f32_16x16x32_f16(a[kt], bf, acc[n], 0,0,0);
    }
  }
}

// in-register LSTM cell: lane owns (4 rows, 1 dim); acc[n][q] = gate n, row q
__device__ __forceinline__ void cell4(const f32x4* acc, const float* b, const float* wx,
                                      const float* x4, float* c, float* h4){
  #pragma unroll
  for (int q=0; q<4; ++q){
    float pi = acc[0][q] + b[0] + x4[q]*wx[0];
    float pf = acc[1][q] + b[1] + x4[q]*wx[1];
    float pg = acc[2][q] + b[2] + x4[q]*wx[2];
    float po = acc[3][q] + b[3] + x4[q]*wx[3];
    float i = sigm(pi), f = sigm(pf), gg = tanh_f(pg), o = sigm(po);
    c[q] = f*c[q] + i*gg;
    h4[q] = o*tanh_f(c[q]);
  }
}

// transpose 16x16 slice through per-wave LDS scratch; store ONE coalesced
// 512B burst (u64 per lane, agent-scope) into member-contiguous layout
__device__ __forceinline__ void storeHn(f16* slotbase, int u, int j, f16* tsc,
                                        const float* h4, int hi, int d, int lane){
  #pragma unroll
  for (int q=0; q<4; ++q) tsc[(hi*4+q)*16 + d] = (f16)h4[q];
  asm volatile("s_waitcnt lgkmcnt(0)" ::: "memory");
  __builtin_amdgcn_sched_barrier(0);
  u64 v = *(const u64*)(tsc + lane*4);
  ast64((u64*)(slotbase + u*4096 + j*256 + lane*4), v);
}

struct P {
  const float *x;
  const float *eWih0,*eWhh0,*eBih0,*eBhh0,*eWih1,*eWhh1,*eBih1,*eBhh1;
  const float *dWih0,*dWhh0,*dBih0,*dBhh0,*dWih1,*dWhh1,*dBih1,*dBhh1;
  const float *fcW,*fcB;
  float* out;
  char* ws;
};

__global__ void initk(char* ws){
  u32* p = (u32*)ws;
  size_t total = (size_t)WS_TOTAL / 4;
  for (size_t k = (size_t)blockIdx.x*blockDim.x + threadIdx.x; k < total;
       k += (size_t)gridDim.x*blockDim.x) p[k] = 0u;
}

__global__ __launch_bounds__(512) void lstm_main(P p){
  const int tid  = threadIdx.x;
  const int lane = tid & 63;
  const int w    = tid >> 6;
  const int chain= w >> 2;         // 0 = L0 chain, 1 = L1 chain
  const int v    = w & 3;          // row-quarter unit
  const int g    = blockIdx.x & 15;
  const int j    = blockIdx.x >> 4;
  const int hi   = lane >> 4;      // row sub-block
  const int d    = lane & 15;      // dim within slice
  const int D    = j*16 + d;       // global h dim
  const int unit = g*4 + v;

  __shared__ __align__(16) char sWL[32768];   // Whh1 / dWhh1 fragments
  __shared__ __align__(16) f16  sTR[8][256];  // per-wave transpose scratch

  f16*   h0buf = (f16*)(p.ws + H0_OFF);
  f16*   h1buf = (f16*)(p.ws + H1_OFF);
  float* ppart = (float*)(p.ws + PP_OFF);
  u32*   F0    = (u32*)(p.ws + F0_OFF);
  u32*   F1    = (u32*)(p.ws + F1_OFF);
  const u32* pF0 = F0 + (g*4 + v)*16;   // one packed 64B line: 16 member dwords
  const u32* pF1 = F1 + (g*4 + v)*16;
  u32* myF0 = F0 + (g*4 + v)*16 + j;
  u32* myF1 = F1 + (g*4 + v)*16 + j;
  f16* tsc = sTR[w];

  int rows[4];
  #pragma unroll
  for (int q=0; q<4; ++q) rows[q] = g*64 + v*16 + hi*4 + q;

  f16x8 B[4][8];
  float c[4] = {0.f,0.f,0.f,0.f};
  float wx[4], b0[4];
  float fcw = 0.f, fcb = 0.f;

  // ---- init: weights into VGPR/LDS ----
  if (chain == 0){
    #pragma unroll
    for (int n=0; n<4; ++n){
      #pragma unroll
      for (int kt=0; kt<8; ++kt)
        B[n][kt] = loadWfrag(p.eWhh0, n*256 + j*16 + d, kt*32 + 8*hi);
      wx[n] = p.eWih0[n*256 + D];
      b0[n] = p.eBih0[n*256 + D] + p.eBhh0[n*256 + D];
    }
  } else {
    #pragma unroll
    for (int n=0; n<4; ++n){
      #pragma unroll
      for (int kt=0; kt<8; ++kt)
        B[n][kt] = loadWfrag(p.eWih1, n*256 + j*16 + d, kt*32 + 8*hi);
      wx[n] = 0.f;
      b0[n] = p.eBih1[n*256 + D] + p.eBhh1[n*256 + D];
    }
    #pragma unroll
    for (int kt=0; kt<8; ++kt)
      *(f16x8*)(sWL + ((v*8+kt)*64 + lane)*16) =
        loadWfrag(p.eWhh1, v*256 + j*16 + d, kt*32 + 8*hi);
  }
  __syncthreads();

  // ================= ENCODER (chains run concurrently) =====================
  if (chain == 0){
    for (int r = 0; r < TENC; ++r){
      float x4[4];
      #pragma unroll
      for (int q=0; q<4; ++q) x4[q] = p.x[rows[q]*TENC + r];
      pollw2(pF0, (u32)r, pF1, (r>=2)?(u32)(r-2):0u, lane);
      f16x8 a[8];
      loadA8n(a, h0buf + ((r+2)%3)*BH + unit*4096, lane);
      f32x4 acc[4] = {{0,0,0,0},{0,0,0,0},{0,0,0,0},{0,0,0,0}};
      mm4(acc, a, B);
      float h4[4];
      cell4(acc, b0, wx, x4, c, h4);
      storeHn(h0buf + (r%3)*BH, unit, j, tsc, h4, hi, d, lane);
      sigw(myF0, (u32)(r+1), lane);
    }
  } else {
    for (int r = 0; r < TENC; ++r){
      pollw2(pF0, (u32)(r+1), pF1, (u32)r, lane);   // h0(r) fresh, h1(r-1)
      f16x8 a0[8], a1[8];
      loadA8n(a0, h0buf + (r%3)*BH + unit*4096, lane);
      loadA8n(a1, h1buf + ((r+1)&1)*BH + unit*4096, lane);
      f32x4 acc[4] = {{0,0,0,0},{0,0,0,0},{0,0,0,0},{0,0,0,0}};
      mm4(acc, a0, B);          // Wih1 * h0(r)
      mm4l(acc, a1, sWL, lane); // Whh1 * h1(r-1)
      float h4[4], xz[4] = {0.f,0.f,0.f,0.f};
      cell4(acc, b0, wx, xz, c, h4);
      storeHn(h1buf + (r&1)*BH, unit, j, tsc, h4, hi, d, lane);
      sigw(myF1, (u32)(r+1), lane);
    }
  }

  // ---- swap to decoder weights ----
  __syncthreads();
  if (chain == 0){
    #pragma unroll
    for (int n=0; n<4; ++n){
      #pragma unroll
      for (int kt=0; kt<8; ++kt)
        B[n][kt] = loadWfrag(p.dWhh0, n*256 + j*16 + d, kt*32 + 8*hi);
      wx[n] = p.dWih0[n*256 + D];
      b0[n] = p.dBih0[n*256 + D] + p.dBhh0[n*256 + D];
    }
    fcb = p.fcB[0];
  } else {
    #pragma unroll
    for (int n=0; n<4; ++n){
      #pragma unroll
      for (int kt=0; kt<8; ++kt)
        B[n][kt] = loadWfrag(p.dWih1, n*256 + j*16 + d, kt*32 + 8*hi);
      b0[n] = p.dBih1[n*256 + D] + p.dBhh1[n*256 + D];
    }
    #pragma unroll
    for (int kt=0; kt<8; ++kt)
      *(f16x8*)(sWL + ((v*8+kt)*64 + lane)*16) =
        loadWfrag(p.dWhh1, v*256 + j*16 + d, kt*32 + 8*hi);
    fcw = p.fcW[D];
  }
  __syncthreads();

  // ================= DECODER (ping-pong between chains) ====================
  if (chain == 0){
    for (int t = 0; t < HORIZ; ++t){
      float inp4[4];
      if (t == 0){
        #pragma unroll
        for (int q=0; q<4; ++q) inp4[q] = p.x[rows[q]*TENC + (TENC-1)];
      }
      pollw2(pF0, (u32)(336+t), pF1, (t==0)?335u:(u32)(336+t), lane);
      if (t > 0){
        float pp4[4];
        #pragma unroll
        for (int q=0; q<4; ++q) pp4[q] = aldf(ppart + ((t-1)&1)*BSZ*16 + rows[q]*16 + d);
        #pragma unroll
        for (int q=0; q<4; ++q){
          float s = pp4[q];
          s += __shfl_xor(s, 1); s += __shfl_xor(s, 2);
          s += __shfl_xor(s, 4); s += __shfl_xor(s, 8);
          inp4[q] = s + fcb;
        }
      }
      f16x8 a[8];
      loadA8n(a, h0buf + ((335+t)%3)*BH + unit*4096, lane);
      f32x4 acc[4] = {{0,0,0,0},{0,0,0,0},{0,0,0,0},{0,0,0,0}};
      mm4(acc, a, B);
      float h4[4];
      cell4(acc, b0, wx, inp4, c, h4);
      storeHn(h0buf + ((336+t)%3)*BH, unit, j, tsc, h4, hi, d, lane);
      if (t > 0 && j == 0 && d == 0){
        #pragma unroll
        for (int q=0; q<4; ++q) p.out[rows[q]*HORIZ + (t-1)] = inp4[q];
      }
      sigw(myF0, (u32)(337+t), lane);
    }
    // final column: pred(167)
    if (j == 0){
      pollw2(pF1, 504u, nullptr, 0, lane);
      #pragma unroll
      for (int q=0; q<4; ++q){
        float s = aldf(ppart + (167&1)*BSZ*16 + rows[q]*16 + d);
        s += __shfl_xor(s, 1); s += __shfl_xor(s, 2);
        s += __shfl_xor(s, 4); s += __shfl_xor(s, 8);
        if (d == 0) p.out[rows[q]*HORIZ + (HORIZ-1)] = s + fcb;
      }
    }
  } else {
    for (int t = 0; t < HORIZ; ++t){
      pollw2(pF0, (u32)(337+t), pF1, (u32)(336+t), lane);  // h0(t) fresh, h1(t-1)
      f16x8 a0[8], a1[8];
      loadA8n(a0, h0buf + ((336+t)%3)*BH + unit*4096, lane);
      loadA8n(a1, h1buf + ((t+1)&1)*BH + unit*4096, lane);
      f32x4 acc[4] = {{0,0,0,0},{0,0,0,0},{0,0,0,0},{0,0,0,0}};
      mm4(acc, a0, B);          // dWih1 * h0(t)
      mm4l(acc, a1, sWL, lane); // dWhh1 * h1(t-1)
      float h4[4], xz[4] = {0.f,0.f,0.f,0.f};
      cell4(acc, b0, wx, xz, c, h4);
      storeHn(h1buf + (t&1)*BH, unit, j, tsc, h4, hi, d, lane);
      // pred partial for this member: sum over our 16 dims
      #pragma unroll
      for (int q=0; q<4; ++q){
        float s = fcw * h4[q];
        s += __shfl_xor(s, 1); s += __shfl_xor(s, 2);
        s += __shfl_xor(s, 4); s += __shfl_xor(s, 8);
        if (d == 0)
          ast32((u32*)(ppart + (t&1)*BSZ*16 + rows[q]*16 + j), __builtin_bit_cast(u32, s));
      }
      sigw(myF1, (u32)(337+t), lane);
    }
  }
}

extern "C" void kernel_launch(void* const* d_in, const int* in_sizes, int n_in,
                              void* d_out, int out_size, void* d_ws, size_t ws_size,
                              hipStream_t stream) {
  (void)in_sizes; (void)n_in; (void)out_size;
  if (ws_size < (size_t)WS_TOTAL) return;  // fail visibly (poisoned output)

  P prm;
  prm.x     = (const float*)d_in[0];
  prm.eWih0 = (const float*)d_in[1];  prm.eWhh0 = (const float*)d_in[2];
  prm.eBih0 = (const float*)d_in[3];  prm.eBhh0 = (const float*)d_in[4];
  prm.eWih1 = (const float*)d_in[5];  prm.eWhh1 = (const float*)d_in[6];
  prm.eBih1 = (const float*)d_in[7];  prm.eBhh1 = (const float*)d_in[8];
  prm.dWih0 = (const float*)d_in[9];  prm.dWhh0 = (const float*)d_in[10];
  prm.dBih0 = (const float*)d_in[11]; prm.dBhh0 = (const float*)d_in[12];
  prm.dWih1 = (const float*)d_in[13]; prm.dWhh1 = (const float*)d_in[14];
  prm.dBih1 = (const float*)d_in[15]; prm.dBhh1 = (const float*)d_in[16];
  prm.fcW   = (const float*)d_in[17]; prm.fcB   = (const float*)d_in[18];
  prm.out   = (float*)d_out;
  prm.ws    = (char*)d_ws;

  hipLaunchKernelGGL(initk, dim3(256), dim3(256), 0, stream, (char*)d_ws);

  void* args[] = { &prm };
  hipLaunchCooperativeKernel((const void*)lstm_main, dim3(256), dim3(512),
                             args, 0, stream);
}

// Round 9
// 4003.005 us; speedup vs baseline: 9.2958x; 2.2694x over previous
//
#include <hip/hip_runtime.h>

#define HIDDEN 256
#define TENC 336
#define HORIZ 168
#define BSZ 1024
#define BH (BSZ*HIDDEN)   // f16 elements per h snapshot (512 KiB)

typedef _Float16 f16;
typedef f16 f16x8 __attribute__((ext_vector_type(8)));
typedef float f32x4 __attribute__((ext_vector_type(4)));
typedef unsigned int u32;
typedef unsigned long long u64;

// ---- workspace layout ----
#define H0_OFF 0                        // 3 slots x 512K
#define H1_OFF (3*BH*2)                 // 2 slots x 512K
#define PP_OFF (H1_OFF + 2*BH*2)        // 2 slots x [1024][16] f32
#define F0_OFF (PP_OFF + 2*BSZ*16*4)    // 1024 member lines x 64B (R6-proven layout)
#define F1_OFF (F0_OFF + 1024*64)
#define WS_TOTAL (F1_OFF + 1024*64)

// ---- dynamic LDS layout ----
#define LDS_W0  0        // Whh0 slice fragments, 32KB
#define LDS_W1I 32768    // Wih1 slice fragments, 32KB
#define LDS_W1H 65536    // Whh1 slice fragments, 32KB
#define LDS_TR  98304    // 8 waves x 256 f16 transpose scratch, 4KB
#define LDS_TOTAL (LDS_TR + 4096)

__device__ __forceinline__ float sigm(float x){ return 1.0f/(1.0f+__expf(-x)); }
__device__ __forceinline__ float tanh_f(float x){ return 2.0f/(1.0f+__expf(-2.0f*x)) - 1.0f; }

// ---- proven agent-scope primitives (R1/R6) ----
__device__ __forceinline__ u64 ald64(const void* p){
  return __hip_atomic_load((const u64*)p, __ATOMIC_RELAXED, __HIP_MEMORY_SCOPE_AGENT);
}
__device__ __forceinline__ u32 ald32(const u32* p){
  return __hip_atomic_load(p, __ATOMIC_RELAXED, __HIP_MEMORY_SCOPE_AGENT);
}
__device__ __forceinline__ float aldf(const float* p){
  return __hip_atomic_load(p, __ATOMIC_RELAXED, __HIP_MEMORY_SCOPE_AGENT);
}
__device__ __forceinline__ void ast32(u32* p, u32 v){
  __hip_atomic_store(p, v, __ATOMIC_RELAXED, __HIP_MEMORY_SCOPE_AGENT);
}
__device__ __forceinline__ void ast64(u64* p, u64 v){
  __hip_atomic_store(p, v, __ATOMIC_RELAXED, __HIP_MEMORY_SCOPE_AGENT);
}

// B-fragment from f32 weights: lane holds W[grow(col=lane&15)][k..k+7]
__device__ __forceinline__ f16x8 loadWfrag(const float* W, int grow, int k){
  const float* p = W + grow*HIDDEN + k;
  float4 lo = *(const float4*)p;
  float4 hi = *(const float4*)(p+4);
  f16x8 r;
  r[0]=(f16)lo.x; r[1]=(f16)lo.y; r[2]=(f16)lo.z; r[3]=(f16)lo.w;
  r[4]=(f16)hi.x; r[5]=(f16)hi.y; r[6]=(f16)hi.z; r[7]=(f16)hi.w;
  return r;
}

// per-wave poll: lanes 0..15 poll f0 member lines (stride 64 u32 = 256B),
// lanes 16..31 poll f1. s_sleep backoff cuts L3 poll slam. R6 semantics.
__device__ __forceinline__ void pollw2(const u32* f0, u32 t0, const u32* f1, u32 t1, int lane){
  const u32* sp = nullptr; u32 tgt = 0;
  if (lane < 16){ sp = f0 + lane*64; tgt = t0; }
  else if (f1 != nullptr && lane < 32){ sp = f1 + (lane-16)*64; tgt = t1; }
  for (int it = 0; it < (1<<20); ++it){
    bool ok = (sp == nullptr) || (ald32(sp) >= tgt);
    if (__all((int)ok)) break;
    __builtin_amdgcn_s_sleep(1);
  }
}

// per-wave release: drain this wave's (uncached) h-stores, then one flag store
__device__ __forceinline__ void sigw(u32* line, u32 v, int lane){
  asm volatile("s_waitcnt vmcnt(0)" ::: "memory");
  if (lane == 0) ast32(line, v);
}

// load 8 A-fragments from member-contiguous layout (coalesced, R8-proven)
__device__ __forceinline__ void loadA8n(f16x8* a, const f16* slotu, int lane){
  const int r16 = (lane & 15) * 16;
  const int h8  = ((lane >> 4) & 1) * 8;
  const int jb  = lane >> 5;
  #pragma unroll
  for (int kt=0; kt<8; ++kt){
    const f16* q = slotu + (kt*2 + jb)*256 + r16 + h8;
    union { u64 w[2]; f16x8 v; } u;
    u.w[0] = ald64(q); u.w[1] = ald64(q+4);
    a[kt] = u.v;
  }
}

// MFMA with B-fragments from LDS (gate-major fragment layout)
__device__ __forceinline__ void mm4l(f32x4* acc, const f16x8* a, const char* WL, int lane){
  #pragma unroll
  for (int kt=0; kt<8; ++kt){
    #pragma unroll
    for (int n=0; n<4; ++n){
      f16x8 bf = *(const f16x8*)(WL + ((n*8+kt)*64 + lane)*16);
      acc[n] = __builtin_amdgcn_mfma_f32_16x16x32_f16(a[kt], bf, acc[n], 0,0,0);
    }
  }
}

// in-register LSTM cell: lane owns (4 rows, 1 dim); acc[n][q] = gate n, row q
__device__ __forceinline__ void cell4(const f32x4* acc, const float* b, const float* wx,
                                      const float* x4, float* c, float* h4){
  #pragma unroll
  for (int q=0; q<4; ++q){
    float pi = acc[0][q] + b[0] + x4[q]*wx[0];
    float pf = acc[1][q] + b[1] + x4[q]*wx[1];
    float pg = acc[2][q] + b[2] + x4[q]*wx[2];
    float po = acc[3][q] + b[3] + x4[q]*wx[3];
    float i = sigm(pi), f = sigm(pf), gg = tanh_f(pg), o = sigm(po);
    c[q] = f*c[q] + i*gg;
    h4[q] = o*tanh_f(c[q]);
  }
}

// transpose 16x16 slice through per-wave LDS scratch; store ONE coalesced
// 512B burst (u64 per lane, agent-scope) into member-contiguous layout
__device__ __forceinline__ void storeHn(f16* slotbase, int u, int j, f16* tsc,
                                        const float* h4, int hi, int d, int lane){
  #pragma unroll
  for (int q=0; q<4; ++q) tsc[(hi*4+q)*16 + d] = (f16)h4[q];
  asm volatile("s_waitcnt lgkmcnt(0)" ::: "memory");
  __builtin_amdgcn_sched_barrier(0);
  u64 v = *(const u64*)(tsc + lane*4);
  ast64((u64*)(slotbase + u*4096 + j*256 + lane*4), v);
}

struct P {
  const float *x;
  const float *eWih0,*eWhh0,*eBih0,*eBhh0,*eWih1,*eWhh1,*eBih1,*eBhh1;
  const float *dWih0,*dWhh0,*dBih0,*dBhh0,*dWih1,*dWhh1,*dBih1,*dBhh1;
  const float *fcW,*fcB;
  float* out;
  char* ws;
};

__global__ void initk(char* ws){
  u32* p = (u32*)ws;
  size_t total = (size_t)WS_TOTAL / 4;
  for (size_t k = (size_t)blockIdx.x*blockDim.x + threadIdx.x; k < total;
       k += (size_t)gridDim.x*blockDim.x) p[k] = 0u;
}

__global__ __launch_bounds__(512) void lstm_main(P p){
  const int tid  = threadIdx.x;
  const int lane = tid & 63;
  const int w    = tid >> 6;
  const int chain= w >> 2;         // 0 = L0 chain, 1 = L1 chain
  const int v    = w & 3;          // row-quarter unit (chain0) / gate (weight init)
  const int g    = blockIdx.x & 15;
  const int j    = blockIdx.x >> 4;
  const int hi   = lane >> 4;      // row sub-block
  const int d    = lane & 15;      // dim within slice
  const int D    = j*16 + d;       // global h dim
  const int unit = g*4 + v;

  extern __shared__ __align__(16) char smem[];
  char* sW0  = smem + LDS_W0;
  char* sW1i = smem + LDS_W1I;
  char* sW1h = smem + LDS_W1H;
  f16*  tsc  = (f16*)(smem + LDS_TR) + w*256;

  f16*   h0buf = (f16*)(p.ws + H0_OFF);
  f16*   h1buf = (f16*)(p.ws + H1_OFF);
  float* ppart = (float*)(p.ws + PP_OFF);
  u32*   F0    = (u32*)(p.ws + F0_OFF);
  u32*   F1    = (u32*)(p.ws + F1_OFF);
  const u32* pF0 = F0 + ((g*16 + 0)*4 + v)*16;   // member stride = 64 u32 (256B)
  const u32* pF1 = F1 + ((g*16 + 0)*4 + v)*16;
  u32* myF0 = F0 + ((g*16 + j)*4 + v)*16;
  u32* myF1 = F1 + ((g*16 + j)*4 + v)*16;

  int rows[4];
  #pragma unroll
  for (int q=0; q<4; ++q) rows[q] = g*64 + v*16 + hi*4 + q;

  float c[4] = {0.f,0.f,0.f,0.f};
  float wx[4], b0[4];
  float fcw = 0.f, fcb = 0.f;

  // ---- init: stage encoder weights into LDS (each wave loads one gate v) ----
  if (chain == 0){
    #pragma unroll
    for (int kt=0; kt<8; ++kt)
      *(f16x8*)(sW0 + ((v*8+kt)*64 + lane)*16) =
        loadWfrag(p.eWhh0, v*256 + j*16 + d, kt*32 + 8*hi);
    #pragma unroll
    for (int n=0; n<4; ++n){
      wx[n] = p.eWih0[n*256 + D];
      b0[n] = p.eBih0[n*256 + D] + p.eBhh0[n*256 + D];
    }
  } else {
    #pragma unroll
    for (int kt=0; kt<8; ++kt){
      *(f16x8*)(sW1i + ((v*8+kt)*64 + lane)*16) =
        loadWfrag(p.eWih1, v*256 + j*16 + d, kt*32 + 8*hi);
      *(f16x8*)(sW1h + ((v*8+kt)*64 + lane)*16) =
        loadWfrag(p.eWhh1, v*256 + j*16 + d, kt*32 + 8*hi);
    }
    wx[0]=wx[1]=wx[2]=wx[3]=0.f;
    #pragma unroll
    for (int n=0; n<4; ++n)
      b0[n] = p.eBih1[n*256 + D] + p.eBhh1[n*256 + D];
  }
  __syncthreads();

  // ================= ENCODER (chains run concurrently) =====================
  if (chain == 0){
    for (int r = 0; r < TENC; ++r){
      float x4[4];
      #pragma unroll
      for (int q=0; q<4; ++q) x4[q] = p.x[rows[q]*TENC + r];
      pollw2(pF0, (u32)r, pF1, (r>=2)?(u32)(r-2):0u, lane);
      f16x8 a[8];
      loadA8n(a, h0buf + ((r+2)%3)*BH + unit*4096, lane);
      f32x4 acc[4] = {{0,0,0,0},{0,0,0,0},{0,0,0,0},{0,0,0,0}};
      mm4l(acc, a, sW0, lane);
      float h4[4];
      cell4(acc, b0, wx, x4, c, h4);
      storeHn(h0buf + (r%3)*BH, unit, j, tsc, h4, hi, d, lane);
      sigw(myF0, (u32)(r+1), lane);
    }
  } else {
    for (int r = 0; r < TENC; ++r){
      pollw2(pF0, (u32)(r+1), pF1, (u32)r, lane);   // h0(r) fresh, h1(r-1)
      f16x8 a0[8], a1[8];
      loadA8n(a0, h0buf + (r%3)*BH + unit*4096, lane);
      loadA8n(a1, h1buf + ((r+1)&1)*BH + unit*4096, lane);
      f32x4 acc[4] = {{0,0,0,0},{0,0,0,0},{0,0,0,0},{0,0,0,0}};
      mm4l(acc, a0, sW1i, lane);  // Wih1 * h0(r)
      mm4l(acc, a1, sW1h, lane);  // Whh1 * h1(r-1)
      float h4[4], xz[4] = {0.f,0.f,0.f,0.f};
      cell4(acc, b0, wx, xz, c, h4);
      storeHn(h1buf + (r&1)*BH, unit, j, tsc, h4, hi, d, lane);
      sigw(myF1, (u32)(r+1), lane);
    }
  }

  // ---- swap to decoder weights ----
  __syncthreads();
  if (chain == 0){
    #pragma unroll
    for (int kt=0; kt<8; ++kt)
      *(f16x8*)(sW0 + ((v*8+kt)*64 + lane)*16) =
        loadWfrag(p.dWhh0, v*256 + j*16 + d, kt*32 + 8*hi);
    #pragma unroll
    for (int n=0; n<4; ++n){
      wx[n] = p.dWih0[n*256 + D];
      b0[n] = p.dBih0[n*256 + D] + p.dBhh0[n*256 + D];
    }
    fcb = p.fcB[0];
  } else {
    #pragma unroll
    for (int kt=0; kt<8; ++kt){
      *(f16x8*)(sW1i + ((v*8+kt)*64 + lane)*16) =
        loadWfrag(p.dWih1, v*256 + j*16 + d, kt*32 + 8*hi);
      *(f16x8*)(sW1h + ((v*8+kt)*64 + lane)*16) =
        loadWfrag(p.dWhh1, v*256 + j*16 + d, kt*32 + 8*hi);
    }
    #pragma unroll
    for (int n=0; n<4; ++n)
      b0[n] = p.dBih1[n*256 + D] + p.dBhh1[n*256 + D];
    fcw = p.fcW[D];
  }
  __syncthreads();

  // ================= DECODER (ping-pong between chains) ====================
  if (chain == 0){
    for (int t = 0; t < HORIZ; ++t){
      float inp4[4];
      if (t == 0){
        #pragma unroll
        for (int q=0; q<4; ++q) inp4[q] = p.x[rows[q]*TENC + (TENC-1)];
      }
      pollw2(pF0, (u32)(336+t), pF1, (t==0)?335u:(u32)(336+t), lane);
      if (t > 0){
        float pp4[4];
        #pragma unroll
        for (int q=0; q<4; ++q) pp4[q] = aldf(ppart + ((t-1)&1)*BSZ*16 + rows[q]*16 + d);
        #pragma unroll
        for (int q=0; q<4; ++q){
          float s = pp4[q];
          s += __shfl_xor(s, 1); s += __shfl_xor(s, 2);
          s += __shfl_xor(s, 4); s += __shfl_xor(s, 8);
          inp4[q] = s + fcb;
        }
      }
      f16x8 a[8];
      loadA8n(a, h0buf + ((335+t)%3)*BH + unit*4096, lane);
      f32x4 acc[4] = {{0,0,0,0},{0,0,0,0},{0,0,0,0},{0,0,0,0}};
      mm4l(acc, a, sW0, lane);
      float h4[4];
      cell4(acc, b0, wx, inp4, c, h4);
      storeHn(h0buf + ((336+t)%3)*BH, unit, j, tsc, h4, hi, d, lane);
      if (t > 0 && j == 0 && d == 0){
        #pragma unroll
        for (int q=0; q<4; ++q) p.out[rows[q]*HORIZ + (t-1)] = inp4[q];
      }
      sigw(myF0, (u32)(337+t), lane);
    }
    // final column: pred(167)
    if (j == 0){
      pollw2(pF1, 504u, nullptr, 0, lane);
      #pragma unroll
      for (int q=0; q<4; ++q){
        float s = aldf(ppart + (167&1)*BSZ*16 + rows[q]*16 + d);
        s += __shfl_xor(s, 1); s += __shfl_xor(s, 2);
        s += __shfl_xor(s, 4); s += __shfl_xor(s, 8);
        if (d == 0) p.out[rows[q]*HORIZ + (HORIZ-1)] = s + fcb;
      }
    }
  } else {
    for (int t = 0; t < HORIZ; ++t){
      pollw2(pF0, (u32)(337+t), pF1, (u32)(336+t), lane);  // h0(t) fresh, h1(t-1)
      f16x8 a0[8], a1[8];
      loadA8n(a0, h0buf + ((336+t)%3)*BH + unit*4096, lane);
      loadA8n(a1, h1buf + ((t+1)&1)*BH + unit*4096, lane);
      f32x4 acc[4] = {{0,0,0,0},{0,0,0,0},{0,0,0,0},{0,0,0,0}};
      mm4l(acc, a0, sW1i, lane);  // dWih1 * h0(t)
      mm4l(acc, a1, sW1h, lane);  // dWhh1 * h1(t-1)
      float h4[4], xz[4] = {0.f,0.f,0.f,0.f};
      cell4(acc, b0, wx, xz, c, h4);
      storeHn(h1buf + (t&1)*BH, unit, j, tsc, h4, hi, d, lane);
      // pred partial for this member: sum over our 16 dims
      #pragma unroll
      for (int q=0; q<4; ++q){
        float s = fcw * h4[q];
        s += __shfl_xor(s, 1); s += __shfl_xor(s, 2);
        s += __shfl_xor(s, 4); s += __shfl_xor(s, 8);
        if (d == 0)
          ast32((u32*)(ppart + (t&1)*BSZ*16 + rows[q]*16 + j), __builtin_bit_cast(u32, s));
      }
      sigw(myF1, (u32)(337+t), lane);
    }
  }
}

extern "C" void kernel_launch(void* const* d_in, const int* in_sizes, int n_in,
                              void* d_out, int out_size, void* d_ws, size_t ws_size,
                              hipStream_t stream) {
  (void)in_sizes; (void)n_in; (void)out_size;
  if (ws_size < (size_t)WS_TOTAL) return;  // fail visibly (poisoned output)

  P prm;
  prm.x     = (const float*)d_in[0];
  prm.eWih0 = (const float*)d_in[1];  prm.eWhh0 = (const float*)d_in[2];
  prm.eBih0 = (const float*)d_in[3];  prm.eBhh0 = (const float*)d_in[4];
  prm.eWih1 = (const float*)d_in[5];  prm.eWhh1 = (const float*)d_in[6];
  prm.eBih1 = (const float*)d_in[7];  prm.eBhh1 = (const float*)d_in[8];
  prm.dWih0 = (const float*)d_in[9];  prm.dWhh0 = (const float*)d_in[10];
  prm.dBih0 = (const float*)d_in[11]; prm.dBhh0 = (const float*)d_in[12];
  prm.dWih1 = (const float*)d_in[13]; prm.dWhh1 = (const float*)d_in[14];
  prm.dBih1 = (const float*)d_in[15]; prm.dBhh1 = (const float*)d_in[16];
  prm.fcW   = (const float*)d_in[17]; prm.fcB   = (const float*)d_in[18];
  prm.out   = (float*)d_out;
  prm.ws    = (char*)d_ws;

  hipLaunchKernelGGL(initk, dim3(256), dim3(256), 0, stream, (char*)d_ws);

  hipFuncSetAttribute((const void*)lstm_main,
                      hipFuncAttributeMaxDynamicSharedMemorySize, LDS_TOTAL);
  void* args[] = { &prm };
  hipLaunchCooperativeKernel((const void*)lstm_main, dim3(256), dim3(512),
                             args, LDS_TOTAL, stream);
}